// Round 1
// 1700.623 us; speedup vs baseline: 1.0364x; 1.0364x over previous
//
#include <hip/hip_runtime.h>
#include <hip/hip_bf16.h>

// 4 stacked LSTM layers (512->64, 64->64, 64->6, 6->6) + FC(6->6).
// B=64, T=1024, M = B*T = 65536.
//
// R6: scan64_coop — the R5 single-wave scan was VALU-issue-bound (VALUBusy
//     5.5% vs a 6.25% ceiling at 64 waves => ~88% per-wave issue busy,
//     ~1125 cyc/step). Split each step across 4 waves: wave g computes gate
//     g only (32 dot2/lane instead of 128), gates exchanged via 2KB
//     double-buffered LDS with ONE raw s_barrier + lgkmcnt(0) per step
//     (no vmcnt(0) drain => xg prefetch and h stores stay in flight).
//     All waves redundantly compute the identical h/c update so the
//     readlane h-broadcast stays in-wave.

#define B_SZ 64
#define T_SZ 1024
#define M_SZ (B_SZ * T_SZ)

typedef _Float16 h2   __attribute__((ext_vector_type(2)));
typedef _Float16 h8   __attribute__((ext_vector_type(8)));
typedef float    f32x4 __attribute__((ext_vector_type(4)));

__device__ __forceinline__ float sigm_f(float x) {
    return 1.0f / (1.0f + __expf(-x));
}
__device__ __forceinline__ float tanh_f(float x) {
    return 2.0f / (1.0f + __expf(-2.0f * x)) - 1.0f;
}

__device__ __forceinline__ float fdot2f(h2 a, h2 b, float c) {
#if __has_builtin(__builtin_amdgcn_fdot2)
    return __builtin_amdgcn_fdot2(a, b, c, false);
#else
    return c + (float)a.x * (float)b.x + (float)a.y * (float)b.y;
#endif
}

// ---------------- fp32 -> f16 converter (for W_ih weights) ------------------
__global__ __launch_bounds__(256) void f32_to_f16(const float* __restrict__ src,
                                                  _Float16* __restrict__ dst, int n) {
    const int i = blockIdx.x * 256 + threadIdx.x;
    if (i < n) dst[i] = (_Float16)src[i];
}

// ---------------- MFMA input-projection GEMM --------------------------------
// out[m, g] = bias[g] + sum_k X[m,k] * W[g,k], G = 256 gates, K in {512, 64}.
template <int K>
__global__ __launch_bounds__(256) void gemm_mfma(const float* __restrict__ X,
                                                 const _Float16* __restrict__ W16,
                                                 const float* __restrict__ bias,
                                                 float* __restrict__ out) {
    const int m0   = blockIdx.x * 64;
    const int tid  = threadIdx.x;
    const int wv   = tid >> 6;
    const int lane = tid & 63;
    const int lh   = lane & 15;
    const int quad = lane >> 4;
    const int n0   = wv * 64;

    __shared__ __align__(16) _Float16 Als[64 * 32];   // 64 rows x 32 k (f16)

    f32x4 acc[4][4];
#pragma unroll
    for (int nt = 0; nt < 4; ++nt) {
        const float bg = bias[n0 + nt * 16 + lh];
#pragma unroll
        for (int mt = 0; mt < 4; ++mt) {
            acc[mt][nt].x = bg; acc[mt][nt].y = bg;
            acc[mt][nt].z = bg; acc[mt][nt].w = bg;
        }
    }

    const int srow = tid >> 2;
    const int sk8  = tid & 3;
    const int sdst = srow * 32 + ((sk8 ^ (srow & 3)) * 8);

    for (int k0 = 0; k0 < K; k0 += 32) {
        const float* xr = X + (size_t)(m0 + srow) * K + k0 + sk8 * 8;
        const float4 a4 = ((const float4*)xr)[0];
        const float4 b4 = ((const float4*)xr)[1];
        h8 bfrag[4];
#pragma unroll
        for (int nt = 0; nt < 4; ++nt) {
            bfrag[nt] = *(const h8*)&W16[(size_t)(n0 + nt * 16 + lh) * K + k0 + quad * 8];
        }
        h8 hv;
        hv[0] = (_Float16)a4.x; hv[1] = (_Float16)a4.y;
        hv[2] = (_Float16)a4.z; hv[3] = (_Float16)a4.w;
        hv[4] = (_Float16)b4.x; hv[5] = (_Float16)b4.y;
        hv[6] = (_Float16)b4.z; hv[7] = (_Float16)b4.w;

        __syncthreads();
        *(h8*)&Als[sdst] = hv;
        __syncthreads();

        h8 afrag[4];
#pragma unroll
        for (int mt = 0; mt < 4; ++mt) {
            const int row = mt * 16 + lh;
            afrag[mt] = *(const h8*)&Als[row * 32 + ((quad ^ (row & 3)) * 8)];
        }
#pragma unroll
        for (int mt = 0; mt < 4; ++mt)
#pragma unroll
            for (int nt = 0; nt < 4; ++nt)
                acc[mt][nt] = __builtin_amdgcn_mfma_f32_16x16x32_f16(
                    afrag[mt], bfrag[nt], acc[mt][nt], 0, 0, 0);
    }

#pragma unroll
    for (int mt = 0; mt < 4; ++mt)
#pragma unroll
        for (int nt = 0; nt < 4; ++nt)
#pragma unroll
            for (int r = 0; r < 4; ++r)
                out[(size_t)(m0 + mt * 16 + quad * 4 + r) * 256 + n0 + nt * 16 + lh] =
                    acc[mt][nt][r];
}

// ---------------- generic small GEMM (thread per output element) -----------
__global__ void gemm_naive(const float* __restrict__ X, const float* __restrict__ W,
                           const float* __restrict__ bias, float* __restrict__ out,
                           int M, int D, int G) {
    const int idx = blockIdx.x * 256 + threadIdx.x;
    if (idx >= M * G) return;
    const int m = idx / G, g = idx % G;
    float acc = bias[g];
    const float* xr = X + (size_t)m * D;
    const float* wr = W + (size_t)g * D;
    for (int k = 0; k < D; ++k) acc += xr[k] * wr[k];
    out[idx] = acc;
}

// ---------------- LSTM scan H=64: 4 waves per batch, gate-per-wave ----------
// Wave g, lane u owns gate g of unit u: 32 packed-f16 weight VGPRs.
// Per step: each wave computes its gate's pre-activation (32 dot2, 4 partial
// accumulators), writes it to LDS, one raw s_barrier (lgkm-only wait, no
// vmcnt drain), then every wave redundantly reads all 4 gates for its unit
// and computes the identical c/h update; h broadcast stays in-wave via
// DPP-pack + readlane. Wave 0 stores h to global.
__global__ __launch_bounds__(256, 1) void scan64_coop(const float* __restrict__ xg,
                                                      const float* __restrict__ whh,
                                                      float* __restrict__ hout) {
    const int b   = blockIdx.x;
    const int tid = threadIdx.x;
    const int g   = tid >> 6;     // gate = wave id
    const int u   = tid & 63;     // unit = lane

    __shared__ float pls[2][4][64];   // [buf][gate][unit]

    // weights: rows g*64+u of whh, packed to f16 pairs
    h2 w[32];
    {
        const float* wr = whh + (size_t)(g * 64 + u) * 64;
#pragma unroll
        for (int k2 = 0; k2 < 32; ++k2) {
            h2 p;
            p.x = (_Float16)wr[2 * k2];
            p.y = (_Float16)wr[2 * k2 + 1];
            w[k2] = p;
        }
    }

    const float* xgb = xg + (size_t)b * T_SZ * 256 + g * 64 + u;
    float xv[4];
#pragma unroll
    for (int s = 0; s < 4; ++s) xv[s] = xgb[(size_t)s * 256];

    float c = 0.0f, h_own = 0.0f;
    float* hrow = hout + (size_t)b * T_SZ * 64 + u;

    for (int t4 = 0; t4 < T_SZ; t4 += 4) {
#pragma unroll
        for (int s = 0; s < 4; ++s) {
            const int t = t4 + s;

            // pack {h[2i], h[2i+1]} into even lanes; broadcast via readlane
            const _Float16 hf = (_Float16)h_own;
            const int hb = (int)__builtin_bit_cast(unsigned short, hf);
            const int nb = __builtin_amdgcn_update_dpp(0, hb, 0xB1, 0xF, 0xF, true);
            const int pk = hb | (nb << 16);

            float acc0 = xv[s], acc1 = 0.0f, acc2 = 0.0f, acc3 = 0.0f;
#pragma unroll
            for (int k8 = 0; k8 < 8; ++k8) {
                const int hs0 = __builtin_amdgcn_readlane(pk, 8 * k8 + 0);
                const int hs1 = __builtin_amdgcn_readlane(pk, 8 * k8 + 2);
                const int hs2 = __builtin_amdgcn_readlane(pk, 8 * k8 + 4);
                const int hs3 = __builtin_amdgcn_readlane(pk, 8 * k8 + 6);
                acc0 = fdot2f(w[4 * k8 + 0], __builtin_bit_cast(h2, hs0), acc0);
                acc1 = fdot2f(w[4 * k8 + 1], __builtin_bit_cast(h2, hs1), acc1);
                acc2 = fdot2f(w[4 * k8 + 2], __builtin_bit_cast(h2, hs2), acc2);
                acc3 = fdot2f(w[4 * k8 + 3], __builtin_bit_cast(h2, hs3), acc3);
            }
            const float a = (acc0 + acc1) + (acc2 + acc3);

            // exchange gates through LDS; raw barrier, lgkm-only wait so the
            // global xg prefetch / h stores stay in flight across the barrier
            pls[t & 1][g][u] = a;
            asm volatile("s_waitcnt lgkmcnt(0)" ::: "memory");
            __builtin_amdgcn_s_barrier();
            asm volatile("" ::: "memory");

            const float p0 = pls[t & 1][0][u];
            const float p1 = pls[t & 1][1][u];
            const float p2 = pls[t & 1][2][u];
            const float p3 = pls[t & 1][3][u];

            // prefetch xg for t+4
            {
                const int tp = (t + 4 < T_SZ) ? (t + 4) : (T_SZ - 1);
                xv[s] = xgb[(size_t)tp * 256];
            }

            // redundant (identical) nonlinearity + state update in all waves
            const float iv = sigm_f(p0);
            const float fv = sigm_f(p1);
            const float gv = tanh_f(p2);
            const float ov = sigm_f(p3);
            c = fv * c + iv * gv;
            h_own = ov * tanh_f(c);

            if (g == 0) hrow[(size_t)t * 64] = h_own;
        }
    }
}

// ---------------- fused L3 + L4 + FC, one wave per batch --------------------
// lanes 0..5: layer-3 unit u; lanes 6..11: layer-4 unit u one step behind;
// FC folded into the h4 broadcast. readlane broadcast, no LDS, no barriers.
__global__ __launch_bounds__(64, 1) void scan66(const float* __restrict__ xg3,
                                                const float* __restrict__ whh3,
                                                const float* __restrict__ wih4,
                                                const float* __restrict__ whh4,
                                                const float* __restrict__ b4,
                                                const float* __restrict__ fcw,
                                                const float* __restrict__ fcb,
                                                float* __restrict__ out) {
    const int b    = blockIdx.x;
    const int lane = threadIdx.x & 63;
    const bool is_l4 = (lane >= 6 && lane < 12);
    const int u = is_l4 ? (lane - 6) : (lane < 6 ? lane : 0);

    float w[4][12];
#pragma unroll
    for (int g = 0; g < 4; ++g) {
#pragma unroll
        for (int k = 0; k < 6; ++k) {
            const float wl3  = whh3[(g * 6 + u) * 6 + k];
            const float wl4i = wih4[(g * 6 + u) * 6 + k];
            const float wl4h = whh4[(g * 6 + u) * 6 + k];
            w[g][k]     = is_l4 ? wl4i : wl3;
            w[g][6 + k] = is_l4 ? wl4h : 0.0f;
        }
    }
    float bias[4], fw[6];
#pragma unroll
    for (int g = 0; g < 4; ++g) bias[g] = is_l4 ? b4[g * 6 + u] : 0.0f;
#pragma unroll
    for (int k = 0; k < 6; ++k) fw[k] = fcw[u * 6 + k];
    const float fb = fcb[u];

    const float* xgb = xg3 + (size_t)b * T_SZ * 24;
    float xv[4][4];
#pragma unroll
    for (int s = 0; s < 4; ++s)
#pragma unroll
        for (int g = 0; g < 4; ++g) xv[s][g] = xgb[s * 24 + g * 6 + u];

    float* outb = out + (size_t)b * T_SZ * 6;
    float h_own = 0.0f, c = 0.0f;

    for (int t4 = 0; t4 < T_SZ + 4; t4 += 4) {
#pragma unroll
        for (int s = 0; s < 4; ++s) {
            const int t = t4 + s;
            const int hbits = __builtin_bit_cast(int, h_own);
            float v[12];
#pragma unroll
            for (int i = 0; i < 12; ++i)
                v[i] = __builtin_bit_cast(float, __builtin_amdgcn_readlane(hbits, i));

            if (is_l4 && t >= 2 && t < T_SZ + 2) {
                outb[(size_t)(t - 2) * 6 + u] =
                    fb + fw[0]*v[6] + fw[1]*v[7] + fw[2]*v[8] +
                         fw[3]*v[9] + fw[4]*v[10] + fw[5]*v[11];
            }

            float p[4];
#pragma unroll
            for (int g = 0; g < 4; ++g) {
                float a = is_l4 ? bias[g] : xv[s][g];
#pragma unroll
                for (int k = 0; k < 12; ++k) a += w[g][k] * v[k];
                p[g] = a;
            }
            {
                const int tp = (t + 4 < T_SZ) ? (t + 4) : (T_SZ - 1);
#pragma unroll
                for (int g = 0; g < 4; ++g)
                    xv[s][g] = xgb[(size_t)tp * 24 + g * 6 + u];
            }
            const float iv = sigm_f(p[0]);
            const float fv = sigm_f(p[1]);
            const float gv = tanh_f(p[2]);
            const float ov = sigm_f(p[3]);
            const float en = (is_l4 && t == 0) ? 0.0f : 1.0f;
            c = en * (fv * c + iv * gv);
            h_own = en * (ov * tanh_f(c));
        }
    }
}

extern "C" void kernel_launch(void* const* d_in, const int* in_sizes, int n_in,
                              void* d_out, int out_size, void* d_ws, size_t ws_size,
                              hipStream_t stream) {
    const float* x      = (const float*)d_in[0];
    const float* w1_ih0 = (const float*)d_in[1];
    const float* w1_hh0 = (const float*)d_in[2];
    const float* b1_0   = (const float*)d_in[3];
    const float* w1_ih1 = (const float*)d_in[4];
    const float* w1_hh1 = (const float*)d_in[5];
    const float* b1_1   = (const float*)d_in[6];
    const float* w2_ih0 = (const float*)d_in[7];
    const float* w2_hh0 = (const float*)d_in[8];
    const float* b2_0   = (const float*)d_in[9];
    const float* w2_ih1 = (const float*)d_in[10];
    const float* w2_hh1 = (const float*)d_in[11];
    const float* b2_1   = (const float*)d_in[12];
    const float* fc_w   = (const float*)d_in[13];
    const float* fc_b   = (const float*)d_in[14];
    float* out = (float*)d_out;

    const int M = M_SZ;
    float* xg = (float*)d_ws;                  // M*256 f32 (reused as xg3)
    float* hA = xg + (size_t)M * 256;          // M*64 f32
    float* hB = hA + (size_t)M * 64;           // M*64 f32
    _Float16* w16a = (_Float16*)(hB + (size_t)M * 64);  // 256*512 f16
    _Float16* w16b = w16a + 256 * 512;                  // 256*64  f16

    f32_to_f16<<<(256 * 512 + 255) / 256, 256, 0, stream>>>(w1_ih0, w16a, 256 * 512);
    f32_to_f16<<<(256 * 64 + 255) / 256, 256, 0, stream>>>(w1_ih1, w16b, 256 * 64);

    // L1: 512 -> 64
    gemm_mfma<512><<<M / 64, 256, 0, stream>>>(x, w16a, b1_0, xg);
    scan64_coop<<<B_SZ, 256, 0, stream>>>(xg, w1_hh0, hA);
    // L2: 64 -> 64
    gemm_mfma<64><<<M / 64, 256, 0, stream>>>(hA, w16b, b1_1, xg);
    scan64_coop<<<B_SZ, 256, 0, stream>>>(xg, w1_hh1, hB);
    // L3 input projection: 64 -> 24 gates
    gemm_naive<<<(M * 24 + 255) / 256, 256, 0, stream>>>(hB, w2_ih0, b2_0, xg, M, 64, 24);
    // L3 + L4 + FC fused
    scan66<<<B_SZ, 64, 0, stream>>>(xg, w2_hh0, w2_ih1, w2_hh1, b2_1, fc_w, fc_b, out);
}

// Round 2
// 1676.891 us; speedup vs baseline: 1.0510x; 1.0142x over previous
//
#include <hip/hip_runtime.h>
#include <hip/hip_bf16.h>

// 4 stacked LSTM layers (512->64, 64->64, 64->6, 6->6) + FC(6->6).
// B=64, T=1024, M = B*T = 65536.
//
// R7: lstm_fused — R6 counters showed the scan is latency-CHAIN-bound
//     (VALUBusy 15% on active SIMDs, ~1060 cy/step vs ~160 cy issue), and we
//     pay that chain 3x serially (scan64 x2 + scan66 ~= 1360 us). Layers form
//     a pipeline across (layer, t): fuse ALL recurrent layers + FC into one
//     kernel, 10 waves/block (4 L1 gate-split, 4 L2 gate-split with in-kernel
//     input projection over [h1|h2], 1 wave L3 with in-kernel 64-wide input
//     projection, 1 wave L4+FC), skewed one step per layer, h exchanged via
//     double-buffered LDS with two raw barriers/iter (lgkm-only waits).
//     Deletes gemm_mfma<64>, gemm_naive, scan66, one f32_to_f16, and the
//     hA/hB global round-trips. Roles overlay one shared register file
//     (wr[64]/wx[8]) to keep VGPR <= ~150 (10-wave block needs <= 168).

#define B_SZ 64
#define T_SZ 1024
#define M_SZ (B_SZ * T_SZ)

typedef _Float16 h2   __attribute__((ext_vector_type(2)));
typedef _Float16 h8   __attribute__((ext_vector_type(8)));
typedef float    f32x4 __attribute__((ext_vector_type(4)));
typedef unsigned u32x4 __attribute__((ext_vector_type(4)));

__device__ __forceinline__ float sigm_f(float x) {
    return 1.0f / (1.0f + __expf(-x));
}
__device__ __forceinline__ float tanh_f(float x) {
    return 2.0f / (1.0f + __expf(-2.0f * x)) - 1.0f;
}

__device__ __forceinline__ float fdot2f(h2 a, h2 b, float c) {
#if __has_builtin(__builtin_amdgcn_fdot2)
    return __builtin_amdgcn_fdot2(a, b, c, false);
#else
    return c + (float)a.x * (float)b.x + (float)a.y * (float)b.y;
#endif
}

__device__ __forceinline__ unsigned pack_h2(float a, float b) {
    h2 p; p.x = (_Float16)a; p.y = (_Float16)b;
    return __builtin_bit_cast(unsigned, p);
}
__device__ __forceinline__ h2 as_h2(unsigned x) { return __builtin_bit_cast(h2, x); }
__device__ __forceinline__ float as_f(unsigned x) { return __builtin_bit_cast(float, x); }
__device__ __forceinline__ float as_f(int x) { return __builtin_bit_cast(float, x); }

// ---------------- fp32 -> f16 converter (for W_ih weights) ------------------
__global__ __launch_bounds__(256) void f32_to_f16(const float* __restrict__ src,
                                                  _Float16* __restrict__ dst, int n) {
    const int i = blockIdx.x * 256 + threadIdx.x;
    if (i < n) dst[i] = (_Float16)src[i];
}

// ---------------- MFMA input-projection GEMM (layer 1 only) -----------------
template <int K>
__global__ __launch_bounds__(256) void gemm_mfma(const float* __restrict__ X,
                                                 const _Float16* __restrict__ W16,
                                                 const float* __restrict__ bias,
                                                 float* __restrict__ out) {
    const int m0   = blockIdx.x * 64;
    const int tid  = threadIdx.x;
    const int wv   = tid >> 6;
    const int lane = tid & 63;
    const int lh   = lane & 15;
    const int quad = lane >> 4;
    const int n0   = wv * 64;

    __shared__ __align__(16) _Float16 Als[64 * 32];

    f32x4 acc[4][4];
#pragma unroll
    for (int nt = 0; nt < 4; ++nt) {
        const float bg = bias[n0 + nt * 16 + lh];
#pragma unroll
        for (int mt = 0; mt < 4; ++mt) {
            acc[mt][nt].x = bg; acc[mt][nt].y = bg;
            acc[mt][nt].z = bg; acc[mt][nt].w = bg;
        }
    }

    const int srow = tid >> 2;
    const int sk8  = tid & 3;
    const int sdst = srow * 32 + ((sk8 ^ (srow & 3)) * 8);

    for (int k0 = 0; k0 < K; k0 += 32) {
        const float* xr = X + (size_t)(m0 + srow) * K + k0 + sk8 * 8;
        const float4 a4 = ((const float4*)xr)[0];
        const float4 b4 = ((const float4*)xr)[1];
        h8 bfrag[4];
#pragma unroll
        for (int nt = 0; nt < 4; ++nt) {
            bfrag[nt] = *(const h8*)&W16[(size_t)(n0 + nt * 16 + lh) * K + k0 + quad * 8];
        }
        h8 hv;
        hv[0] = (_Float16)a4.x; hv[1] = (_Float16)a4.y;
        hv[2] = (_Float16)a4.z; hv[3] = (_Float16)a4.w;
        hv[4] = (_Float16)b4.x; hv[5] = (_Float16)b4.y;
        hv[6] = (_Float16)b4.z; hv[7] = (_Float16)b4.w;

        __syncthreads();
        *(h8*)&Als[sdst] = hv;
        __syncthreads();

        h8 afrag[4];
#pragma unroll
        for (int mt = 0; mt < 4; ++mt) {
            const int row = mt * 16 + lh;
            afrag[mt] = *(const h8*)&Als[row * 32 + ((quad ^ (row & 3)) * 8)];
        }
#pragma unroll
        for (int mt = 0; mt < 4; ++mt)
#pragma unroll
            for (int nt = 0; nt < 4; ++nt)
                acc[mt][nt] = __builtin_amdgcn_mfma_f32_16x16x32_f16(
                    afrag[mt], bfrag[nt], acc[mt][nt], 0, 0, 0);
    }

#pragma unroll
    for (int mt = 0; mt < 4; ++mt)
#pragma unroll
        for (int nt = 0; nt < 4; ++nt)
#pragma unroll
            for (int r = 0; r < 4; ++r)
                out[(size_t)(m0 + mt * 16 + quad * 4 + r) * 256 + n0 + nt * 16 + lh] =
                    acc[mt][nt][r];
}

// ---------------- fused pipelined scan: L1 + L2 + L3 + L4 + FC --------------
// One block per batch, 10 waves. Skews: at iter s, L1 computes h1[s],
// L2 computes h2[s-1], L3 (wave 8) computes h3[s-2], L4 (wave 9) computes
// h4[s-3], FC writes out[s-4]. Loop runs s = 0 .. T+3.
__global__ __launch_bounds__(640, 1) void lstm_fused(
        const float* __restrict__ xg1,    // [B,T,256]  (b1_0 already added)
        const float* __restrict__ whh1,   // [256][64]
        const float* __restrict__ wih2,   // [256][64]
        const float* __restrict__ whh2,   // [256][64]
        const float* __restrict__ b2v,    // [256]
        const float* __restrict__ wih3,   // [24][64]
        const float* __restrict__ whh3,   // [24][6]
        const float* __restrict__ b3v,    // [24]
        const float* __restrict__ wih4,   // [24][6]
        const float* __restrict__ whh4,   // [24][6]
        const float* __restrict__ b4v,    // [24]
        const float* __restrict__ fcw,    // [6][6]
        const float* __restrict__ fcb,    // [6]
        float* __restrict__ out) {        // [B,T,6]
    const int b   = blockIdx.x;
    const int tid = threadIdx.x;
    const int wid = tid >> 6;
    const int u   = tid & 63;

    __shared__ __align__(16) float    g1ls[2][4][64];
    __shared__ __align__(16) float    g2ls[2][4][64];
    __shared__ __align__(16) unsigned h1pk[2][32];
    __shared__ __align__(16) float    h2f[2][64];
    __shared__ __align__(16) float    h3f[2][8];

    // shared (overlaid) register file across roles
    unsigned wr[64];
    float    wx[8];
#pragma unroll
    for (int i = 0; i < 8; ++i) wx[i] = 0.0f;

    const float* xgb = xg1 + (size_t)b * T_SZ * 256 + (wid & 3) * 64 + u;
    float xv0 = 0.0f, xv1 = 0.0f;
    float hS = 0.0f, cS = 0.0f;
    int   pkS = 0;
    const int uu4 = 4 * (u % 6);

    if (wid < 4) {
        // L1: whh1 rows (g*64+u) as 32 packed-f16 pairs
        const float* wrow = whh1 + (size_t)(wid * 64 + u) * 64;
#pragma unroll
        for (int k2 = 0; k2 < 32; ++k2) wr[k2] = pack_h2(wrow[2 * k2], wrow[2 * k2 + 1]);
        xv0 = xgb[0];
        xv1 = xgb[256];
    } else if (wid < 8) {
        // L2: wih2 rows in wr[0:32), whh2 rows in wr[32:64)
        const int g = wid - 4;
        const float* wi = wih2 + (size_t)(g * 64 + u) * 64;
        const float* wh = whh2 + (size_t)(g * 64 + u) * 64;
#pragma unroll
        for (int k2 = 0; k2 < 32; ++k2) {
            wr[k2]      = pack_h2(wi[2 * k2], wi[2 * k2 + 1]);
            wr[32 + k2] = pack_h2(wh[2 * k2], wh[2 * k2 + 1]);
        }
        wx[0] = b2v[g * 64 + u];
    } else if (wid == 8) {
        // L3: wih3 row q as 64 f32 (full precision), whh3 row in wx[0:6)
        const int q = (u < 24) ? u : 23;
#pragma unroll
        for (int j = 0; j < 64; ++j)
            wr[j] = __builtin_bit_cast(unsigned, wih3[(size_t)q * 64 + j]);
#pragma unroll
        for (int k = 0; k < 6; ++k) wx[k] = whh3[q * 6 + k];
        wx[6] = b3v[q];
    } else {
        // L4 + FC: lanes 0-5 hold L4 unit u (w in wr[0:48)), lanes 6-11 hold
        // FC row u-6 (w in wr[48:54)).
        const int q4 = (u < 6) ? u : 0;
        const int qf = (u >= 6 && u < 12) ? (u - 6) : 0;
#pragma unroll
        for (int g = 0; g < 4; ++g) {
#pragma unroll
            for (int k = 0; k < 6; ++k) {
                wr[g * 12 + k]     = __builtin_bit_cast(unsigned, wih4[(g * 6 + q4) * 6 + k]);
                wr[g * 12 + 6 + k] = __builtin_bit_cast(unsigned, whh4[(g * 6 + q4) * 6 + k]);
            }
            wx[g] = b4v[g * 6 + q4];
        }
#pragma unroll
        for (int k = 0; k < 6; ++k) wr[48 + k] = __builtin_bit_cast(unsigned, fcw[qf * 6 + k]);
        wx[4] = fcb[qf];
    }

    float* outb = out + (size_t)b * T_SZ * 6;

    for (int s2 = 0; s2 < T_SZ + 4; s2 += 2) {
#pragma unroll
        for (int half = 0; half < 2; ++half) {
            const int s   = s2 + half;
            const int cur = half;
            const int prv = half ^ 1;

            // ================= phase A: gate pre-activations =================
            float aGate = 0.0f;
            if (wid < 4) {
                if (s < T_SZ) {
                    float a0 = (half ? xv1 : xv0), a1 = 0.f, a2 = 0.f, a3 = 0.f;
#pragma unroll
                    for (int k8 = 0; k8 < 8; ++k8) {
                        const int hs0 = __builtin_amdgcn_readlane(pkS, 8 * k8 + 0);
                        const int hs1 = __builtin_amdgcn_readlane(pkS, 8 * k8 + 2);
                        const int hs2 = __builtin_amdgcn_readlane(pkS, 8 * k8 + 4);
                        const int hs3 = __builtin_amdgcn_readlane(pkS, 8 * k8 + 6);
                        a0 = fdot2f(as_h2(wr[4 * k8 + 0]), __builtin_bit_cast(h2, hs0), a0);
                        a1 = fdot2f(as_h2(wr[4 * k8 + 1]), __builtin_bit_cast(h2, hs1), a1);
                        a2 = fdot2f(as_h2(wr[4 * k8 + 2]), __builtin_bit_cast(h2, hs2), a2);
                        a3 = fdot2f(as_h2(wr[4 * k8 + 3]), __builtin_bit_cast(h2, hs3), a3);
                    }
                    aGate = (a0 + a1) + (a2 + a3);
                    // prefetch xg for s+2
                    const int tp = (s + 2 < T_SZ) ? (s + 2) : (T_SZ - 1);
                    const float xnew = xgb[(size_t)tp * 256];
                    if (half) xv1 = xnew; else xv0 = xnew;
                }
            } else if (wid < 8) {
                if (s >= 1 && s <= T_SZ) {
                    float a0 = wx[0], a1 = 0.f, a2 = 0.f, a3 = 0.f;
                    float c0 = 0.f, c1 = 0.f, c2 = 0.f, c3 = 0.f;
                    // h1[s-1] from LDS packed pairs (broadcast reads)
                    const u32x4* hp = (const u32x4*)&h1pk[prv][0];
#pragma unroll
                    for (int r = 0; r < 8; ++r) {
                        const u32x4 q = hp[r];
                        a0 = fdot2f(as_h2(wr[4 * r + 0]), as_h2(q[0]), a0);
                        a1 = fdot2f(as_h2(wr[4 * r + 1]), as_h2(q[1]), a1);
                        a2 = fdot2f(as_h2(wr[4 * r + 2]), as_h2(q[2]), a2);
                        a3 = fdot2f(as_h2(wr[4 * r + 3]), as_h2(q[3]), a3);
                    }
                    // h2[s-2] from own registers via readlane
#pragma unroll
                    for (int k8 = 0; k8 < 8; ++k8) {
                        const int hs0 = __builtin_amdgcn_readlane(pkS, 8 * k8 + 0);
                        const int hs1 = __builtin_amdgcn_readlane(pkS, 8 * k8 + 2);
                        const int hs2 = __builtin_amdgcn_readlane(pkS, 8 * k8 + 4);
                        const int hs3 = __builtin_amdgcn_readlane(pkS, 8 * k8 + 6);
                        c0 = fdot2f(as_h2(wr[32 + 4 * k8 + 0]), __builtin_bit_cast(h2, hs0), c0);
                        c1 = fdot2f(as_h2(wr[32 + 4 * k8 + 1]), __builtin_bit_cast(h2, hs1), c1);
                        c2 = fdot2f(as_h2(wr[32 + 4 * k8 + 2]), __builtin_bit_cast(h2, hs2), c2);
                        c3 = fdot2f(as_h2(wr[32 + 4 * k8 + 3]), __builtin_bit_cast(h2, hs3), c3);
                    }
                    aGate = ((a0 + a1) + (a2 + a3)) + ((c0 + c1) + (c2 + c3));
                }
            } else if (wid == 8) {
                // L3 at t3 = s-2
                const int t3 = s - 2;
                if (t3 >= 0 && t3 < T_SZ) {
                    float d[8] = {wx[6], 0.f, 0.f, 0.f, 0.f, 0.f, 0.f, 0.f};
                    const f32x4* h2p = (const f32x4*)&h2f[prv][0];
#pragma unroll
                    for (int r = 0; r < 16; ++r) {
                        const f32x4 hv4 = h2p[r];
                        const int o = (r & 1) * 4;
                        d[o + 0] = fmaf(as_f(wr[4 * r + 0]), hv4[0], d[o + 0]);
                        d[o + 1] = fmaf(as_f(wr[4 * r + 1]), hv4[1], d[o + 1]);
                        d[o + 2] = fmaf(as_f(wr[4 * r + 2]), hv4[2], d[o + 2]);
                        d[o + 3] = fmaf(as_f(wr[4 * r + 3]), hv4[3], d[o + 3]);
                    }
                    // recurrent term: h3[t3-1] broadcast from own lanes 0-5
                    const int hb3 = __builtin_bit_cast(int, hS);
#pragma unroll
                    for (int k = 0; k < 6; ++k)
                        d[k] = fmaf(wx[k], as_f(__builtin_amdgcn_readlane(hb3, k)), d[k]);
                    const float p = ((d[0] + d[1]) + (d[2] + d[3])) +
                                    ((d[4] + d[5]) + (d[6] + d[7]));
                    // gate exchange: lanes 0-5 gather p at lanes uu, uu+6, uu+12, uu+18
                    const int pb = __builtin_bit_cast(int, p);
                    const float p0 = as_f(__builtin_amdgcn_ds_bpermute(uu4, pb));
                    const float p1 = as_f(__builtin_amdgcn_ds_bpermute(uu4 + 24, pb));
                    const float p2 = as_f(__builtin_amdgcn_ds_bpermute(uu4 + 48, pb));
                    const float p3 = as_f(__builtin_amdgcn_ds_bpermute(uu4 + 72, pb));
                    if (u < 6) {
                        const float iv = sigm_f(p0);
                        const float fv = sigm_f(p1);
                        const float gv = tanh_f(p2);
                        const float ov = sigm_f(p3);
                        cS = fv * cS + iv * gv;
                        hS = ov * tanh_f(cS);
                        h3f[cur][u] = hS;
                    }
                }
            } else {
                // L4 at t4 = s-3 ; FC writes out[t4-1]
                const int t4 = s - 3;
                const int hb4 = __builtin_bit_cast(int, hS);
                float v4[6];
#pragma unroll
                for (int k = 0; k < 6; ++k)
                    v4[k] = as_f(__builtin_amdgcn_readlane(hb4, k));
                const int tout = t4 - 1;
                if (tout >= 0 && tout < T_SZ) {
                    if (u >= 6 && u < 12) {
                        float o = wx[4];
#pragma unroll
                        for (int k = 0; k < 6; ++k) o = fmaf(as_f(wr[48 + k]), v4[k], o);
                        outb[(size_t)tout * 6 + (u - 6)] = o;
                    }
                }
                if (t4 >= 0 && t4 < T_SZ) {
                    float v[12];
#pragma unroll
                    for (int k = 0; k < 6; ++k) v[k] = h3f[prv][k];   // h3[t4]
#pragma unroll
                    for (int k = 0; k < 6; ++k) v[6 + k] = v4[k];     // h4[t4-1]
                    float pg[4];
#pragma unroll
                    for (int g = 0; g < 4; ++g) {
                        float a = wx[g];
#pragma unroll
                        for (int k = 0; k < 12; ++k) a = fmaf(as_f(wr[g * 12 + k]), v[k], a);
                        pg[g] = a;
                    }
                    if (u < 6) {
                        const float iv = sigm_f(pg[0]);
                        const float fv = sigm_f(pg[1]);
                        const float gv = tanh_f(pg[2]);
                        const float ov = sigm_f(pg[3]);
                        cS = fv * cS + iv * gv;
                        hS = ov * tanh_f(cS);
                    }
                }
            }

            // ---- write gate pre-activations ----
            if (wid < 4) {
                if (s < T_SZ) g1ls[cur][wid][u] = aGate;
            } else if (wid < 8) {
                if (s >= 1 && s <= T_SZ) g2ls[cur][wid - 4][u] = aGate;
            }

            asm volatile("s_waitcnt lgkmcnt(0)" ::: "memory");
            __builtin_amdgcn_s_barrier();
            asm volatile("" ::: "memory");

            // ================= phase C: nonlinearity + h updates =============
            if (wid < 4 && s < T_SZ) {
                const float p0 = g1ls[cur][0][u];
                const float p1 = g1ls[cur][1][u];
                const float p2 = g1ls[cur][2][u];
                const float p3 = g1ls[cur][3][u];
                const float iv = sigm_f(p0);
                const float fv = sigm_f(p1);
                const float gv = tanh_f(p2);
                const float ov = sigm_f(p3);
                cS = fv * cS + iv * gv;
                hS = ov * tanh_f(cS);
                const _Float16 hf = (_Float16)hS;
                const int hb = (int)__builtin_bit_cast(unsigned short, hf);
                const int nb = __builtin_amdgcn_update_dpp(0, hb, 0xB1, 0xF, 0xF, true);
                pkS = hb | (nb << 16);
                if (wid == 0 && !(u & 1)) h1pk[cur][u >> 1] = (unsigned)pkS;
            } else if (wid >= 4 && wid < 8 && s >= 1 && s <= T_SZ) {
                const float p0 = g2ls[cur][0][u];
                const float p1 = g2ls[cur][1][u];
                const float p2 = g2ls[cur][2][u];
                const float p3 = g2ls[cur][3][u];
                const float iv = sigm_f(p0);
                const float fv = sigm_f(p1);
                const float gv = tanh_f(p2);
                const float ov = sigm_f(p3);
                cS = fv * cS + iv * gv;
                hS = ov * tanh_f(cS);
                const _Float16 hf = (_Float16)hS;
                const int hb = (int)__builtin_bit_cast(unsigned short, hf);
                const int nb = __builtin_amdgcn_update_dpp(0, hb, 0xB1, 0xF, 0xF, true);
                pkS = hb | (nb << 16);
                if (wid == 4) h2f[cur][u] = hS;
            }

            asm volatile("s_waitcnt lgkmcnt(0)" ::: "memory");
            __builtin_amdgcn_s_barrier();
            asm volatile("" ::: "memory");
        }
    }
}

extern "C" void kernel_launch(void* const* d_in, const int* in_sizes, int n_in,
                              void* d_out, int out_size, void* d_ws, size_t ws_size,
                              hipStream_t stream) {
    const float* x      = (const float*)d_in[0];
    const float* w1_ih0 = (const float*)d_in[1];
    const float* w1_hh0 = (const float*)d_in[2];
    const float* b1_0   = (const float*)d_in[3];
    const float* w1_ih1 = (const float*)d_in[4];
    const float* w1_hh1 = (const float*)d_in[5];
    const float* b1_1   = (const float*)d_in[6];
    const float* w2_ih0 = (const float*)d_in[7];
    const float* w2_hh0 = (const float*)d_in[8];
    const float* b2_0   = (const float*)d_in[9];
    const float* w2_ih1 = (const float*)d_in[10];
    const float* w2_hh1 = (const float*)d_in[11];
    const float* b2_1   = (const float*)d_in[12];
    const float* fc_w   = (const float*)d_in[13];
    const float* fc_b   = (const float*)d_in[14];
    float* out = (float*)d_out;

    const int M = M_SZ;
    float* xg = (float*)d_ws;                           // M*256 f32
    _Float16* w16a = (_Float16*)(xg + (size_t)M * 256); // 256*512 f16

    f32_to_f16<<<(256 * 512 + 255) / 256, 256, 0, stream>>>(w1_ih0, w16a, 256 * 512);

    // L1 input projection (x known upfront): 512 -> 256 gates, bias folded
    gemm_mfma<512><<<M / 64, 256, 0, stream>>>(x, w16a, b1_0, xg);

    // everything recurrent, pipelined in one kernel
    lstm_fused<<<B_SZ, 640, 0, stream>>>(xg, w1_hh0,
                                         w1_ih1, w1_hh1, b1_1,
                                         w2_ih0, w2_hh0, b2_0,
                                         w2_ih1, w2_hh1, b2_1,
                                         fc_w, fc_b, out);
}